// Round 2
// baseline (746.922 us; speedup 1.0000x reference)
//
#include <hip/hip_runtime.h>
#include <hip/hip_bf16.h>
#include <stdint.h>

#define IN_F   64
#define OH     256      // OUT * H
#define HEADS  4
#define SLOPE  0.2f
#define TN     32       // nodes per block in projection

// ---------------- K0: zero deg + counter ----------------
__global__ __launch_bounds__(256) void zero_kernel(int* __restrict__ a, int* __restrict__ b, int N) {
    int i = blockIdx.x * 256 + threadIdx.x;
    if (i < N) { a[i] = 0; b[i] = 0; }
}

// ---------------- K1: Z = feat @ W^T + bias (fp32) ----------------
__global__ __launch_bounds__(256) void proj_kernel(
    const float4* __restrict__ feat4,
    const float4* __restrict__ W4,
    const float* __restrict__ bias,
    float* __restrict__ Z, int N)
{
    __shared__ float featS[TN][IN_F];
    int t = threadIdx.x;
    int nodeBase = blockIdx.x * TN;

    // load feat tile (TN x 64 floats = TN x 16 float4), coalesced
    for (int p = t; p < TN * 16; p += 256) {
        int n = p >> 4, kk = p & 15;
        int gn = nodeBase + n;
        float4 v = make_float4(0.f, 0.f, 0.f, 0.f);
        if (gn < N) v = feat4[(size_t)gn * 16 + kk];
        featS[n][kk * 4 + 0] = v.x; featS[n][kk * 4 + 1] = v.y;
        featS[n][kk * 4 + 2] = v.z; featS[n][kk * 4 + 3] = v.w;
    }

    // W row o = t into registers (64 floats)
    float Wf[64];
    int o = t;
    #pragma unroll
    for (int q = 0; q < 16; q++) {
        float4 w = W4[o * 16 + q];
        Wf[q * 4 + 0] = w.x; Wf[q * 4 + 1] = w.y;
        Wf[q * 4 + 2] = w.z; Wf[q * 4 + 3] = w.w;
    }
    float b = bias[o];
    __syncthreads();

    for (int n = 0; n < TN; n++) {
        int gn = nodeBase + n;
        if (gn >= N) break;
        float a = b;
        #pragma unroll
        for (int k = 0; k < 64; k++) a += featS[n][k] * Wf[k];
        Z[(size_t)gn * OH + o] = a;
    }
}

// ---------------- K2: e_l / e_r per node (wave per node) ----------------
__global__ __launch_bounds__(256) void elr_kernel(
    const float4* __restrict__ Z4,
    const float4* __restrict__ al4, const float4* __restrict__ ar4,
    float4* __restrict__ el4, float4* __restrict__ er4, int N)
{
    int lane = threadIdx.x & 63;
    int node = blockIdx.x * 4 + (threadIdx.x >> 6);
    if (node >= N) return;
    float4 z = Z4[(size_t)node * 64 + lane];   // elements d=lane, h=0..3
    float4 ua = al4[lane], ub = ar4[lane];
    float pl0 = z.x * ua.x, pl1 = z.y * ua.y, pl2 = z.z * ua.z, pl3 = z.w * ua.w;
    float pr0 = z.x * ub.x, pr1 = z.y * ub.y, pr2 = z.z * ub.z, pr3 = z.w * ub.w;
    #pragma unroll
    for (int off = 1; off < 64; off <<= 1) {
        pl0 += __shfl_xor(pl0, off); pl1 += __shfl_xor(pl1, off);
        pl2 += __shfl_xor(pl2, off); pl3 += __shfl_xor(pl3, off);
        pr0 += __shfl_xor(pr0, off); pr1 += __shfl_xor(pr1, off);
        pr2 += __shfl_xor(pr2, off); pr3 += __shfl_xor(pr3, off);
    }
    if (lane == 0) {
        el4[node] = make_float4(pl0, pl1, pl2, pl3);
        er4[node] = make_float4(pr0, pr1, pr2, pr3);
    }
}

// ---------------- K3: degree histogram ----------------
__global__ __launch_bounds__(256) void hist_kernel(const int* __restrict__ row, int* __restrict__ deg, int E) {
    int e = blockIdx.x * 256 + threadIdx.x;
    if (e < E) atomicAdd(&deg[row[e]], 1);
}

// ---------------- K4: per-chunk sums (chunk = 1024) ----------------
__global__ __launch_bounds__(256) void scan_sums(const int* __restrict__ deg, int* __restrict__ bsums, int N) {
    __shared__ int lds[256];
    int t = threadIdx.x;
    int base = blockIdx.x * 1024;
    int v = 0;
    for (int q = 0; q < 4; q++) { int g = base + t * 4 + q; if (g < N) v += deg[g]; }
    lds[t] = v; __syncthreads();
    for (int off = 128; off >= 1; off >>= 1) {
        if (t < off) lds[t] += lds[t + off];
        __syncthreads();
    }
    if (t == 0) bsums[blockIdx.x] = lds[0];
}

// ---------------- K5: exclusive scan of chunk sums (tiny) ----------------
__global__ void scan_top(int* __restrict__ bsums, int nb) {
    if (blockIdx.x == 0 && threadIdx.x == 0) {
        int run = 0;
        for (int i = 0; i < nb; i++) { int v = bsums[i]; bsums[i] = run; run += v; }
    }
}

// ---------------- K6: per-chunk exclusive scan -> offsets ----------------
__global__ __launch_bounds__(256) void scan_chunks(
    const int* __restrict__ deg, const int* __restrict__ bsums,
    int* __restrict__ offs, int N)
{
    __shared__ int lds[256];
    int t = threadIdx.x;
    int base = blockIdx.x * 1024;
    int vals[4]; int s = 0;
    for (int q = 0; q < 4; q++) { int g = base + t * 4 + q; vals[q] = (g < N) ? deg[g] : 0; s += vals[q]; }
    lds[t] = s; __syncthreads();
    for (int off = 1; off < 256; off <<= 1) {
        int add = (t >= off) ? lds[t - off] : 0;
        __syncthreads();
        lds[t] += add;
        __syncthreads();
    }
    int prefix = bsums[blockIdx.x] + (t > 0 ? lds[t - 1] : 0);
    for (int q = 0; q < 4; q++) {
        int g = base + t * 4 + q;
        if (g < N) { offs[g] = prefix; prefix += vals[q]; }
    }
}

// ---------------- K7: scatter edges into CSR by destination ----------------
__global__ __launch_bounds__(256) void scatter_kernel(
    const int* __restrict__ row, const int* __restrict__ col,
    const int* __restrict__ offs, int* __restrict__ cnt,
    int* __restrict__ csr, int E)
{
    int e = blockIdx.x * 256 + threadIdx.x;
    if (e < E) {
        int r = row[e];
        int pos = offs[r] + atomicAdd(&cnt[r], 1);
        csr[pos] = col[e];
    }
}

// ---------------- K8: fused segment softmax + weighted aggregation ----------------
__global__ __launch_bounds__(256) void gat_aggregate(
    const float* __restrict__ Z, const float* __restrict__ el,
    const float* __restrict__ er, const int* __restrict__ offs,
    const int* __restrict__ deg, const int* __restrict__ csr,
    float* __restrict__ out, int N)
{
    __shared__ float s_red[256];
    __shared__ float s_al[64 * 4];
    __shared__ int   s_col[64];
    __shared__ float m4[4], s4[4];

    int i = blockIdx.x;
    int t = threadIdx.x;
    int j = t >> 2, h = t & 3;
    int start = offs[i], dg = deg[i];
    float elh = el[(size_t)i * 4 + h];

    // Phase A: per-head max over incoming edges
    float mymax = -1e30f;
    for (int base = 0; base < dg; base += 64) {
        int jj = base + j;
        if (jj < dg) {
            int c = csr[start + jj];
            float sc = elh + er[(size_t)c * 4 + h];
            sc = sc > 0.f ? sc : SLOPE * sc;
            mymax = fmaxf(mymax, sc);
        }
    }
    s_red[t] = mymax; __syncthreads();
    for (int off = 128; off >= 4; off >>= 1) {
        if (t < off) s_red[t] = fmaxf(s_red[t], s_red[t + off]);
        __syncthreads();
    }
    if (t < 4) m4[t] = s_red[t];
    __syncthreads();
    float mh = m4[h];

    // Phase B: per-head sum of exp
    float mysum = 0.f;
    for (int base = 0; base < dg; base += 64) {
        int jj = base + j;
        if (jj < dg) {
            int c = csr[start + jj];
            float sc = elh + er[(size_t)c * 4 + h];
            sc = sc > 0.f ? sc : SLOPE * sc;
            mysum += __expf(sc - mh);
        }
    }
    s_red[t] = mysum; __syncthreads();
    for (int off = 128; off >= 4; off >>= 1) {
        if (t < off) s_red[t] += s_red[t + off];
        __syncthreads();
    }
    if (t < 4) s4[t] = s_red[t];
    __syncthreads();
    float invs = s4[h] > 0.f ? 1.0f / s4[h] : 0.f;

    // Phase C: alpha in LDS chunk-wise, gather-accumulate Z[col]
    float acc = 0.f;
    for (int base = 0; base < dg; base += 64) {
        int cnt = min(64, dg - base);
        if (j < cnt) {
            int c = csr[start + base + j];
            float sc = elh + er[(size_t)c * 4 + h];
            sc = sc > 0.f ? sc : SLOPE * sc;
            s_al[j * 4 + h] = __expf(sc - mh) * invs;
            if (h == 0) s_col[j] = c;
        }
        __syncthreads();
        #pragma unroll 4
        for (int q = 0; q < cnt; q++) {
            acc += s_al[q * 4 + h] * Z[(size_t)s_col[q] * OH + t];
        }
        __syncthreads();
    }
    out[(size_t)i * OH + t] = acc;
}

// ---------------- launch ----------------
extern "C" void kernel_launch(void* const* d_in, const int* in_sizes, int n_in,
                              void* d_out, int out_size, void* d_ws, size_t ws_size,
                              hipStream_t stream)
{
    const float* feat  = (const float*)d_in[0];
    const float* W     = (const float*)d_in[1];
    const float* bias  = (const float*)d_in[2];
    const float* a_l   = (const float*)d_in[3];
    const float* a_r   = (const float*)d_in[4];
    const int*   row   = (const int*)d_in[5];
    const int*   col   = (const int*)d_in[6];
    float* out = (float*)d_out;

    int N = in_sizes[0] / IN_F;
    int E = in_sizes[5];

    char* ws = (char*)d_ws;
    size_t off = 0;
    auto alloc = [&](size_t bytes) -> void* {
        void* p = (void*)(ws + off);
        off += (bytes + 255) & ~(size_t)255;
        return p;
    };
    float* Z     = (float*)alloc((size_t)N * OH * sizeof(float));   // 102.4 MB
    float* el    = (float*)alloc((size_t)N * 4 * sizeof(float));
    float* er    = (float*)alloc((size_t)N * 4 * sizeof(float));
    int*   deg   = (int*)alloc((size_t)N * sizeof(int));
    int*   cnt   = (int*)alloc((size_t)N * sizeof(int));
    int*   offs  = (int*)alloc((size_t)N * sizeof(int));
    int*   bsums = (int*)alloc(4096);
    int*   csr   = (int*)alloc((size_t)E * sizeof(int));
    (void)ws_size; (void)n_in; (void)out_size;

    int NB = (N + 1023) / 1024;

    zero_kernel<<<(N + 255) / 256, 256, 0, stream>>>(deg, cnt, N);
    proj_kernel<<<(N + TN - 1) / TN, 256, 0, stream>>>(
        (const float4*)feat, (const float4*)W, bias, Z, N);
    elr_kernel<<<(N + 3) / 4, 256, 0, stream>>>(
        (const float4*)Z, (const float4*)a_l, (const float4*)a_r,
        (float4*)el, (float4*)er, N);
    hist_kernel<<<(E + 255) / 256, 256, 0, stream>>>(row, deg, E);
    scan_sums<<<NB, 256, 0, stream>>>(deg, bsums, N);
    scan_top<<<1, 64, 0, stream>>>(bsums, NB);
    scan_chunks<<<NB, 256, 0, stream>>>(deg, bsums, offs, N);
    scatter_kernel<<<(E + 255) / 256, 256, 0, stream>>>(row, col, offs, cnt, csr, E);
    gat_aggregate<<<N, 256, 0, stream>>>(Z, el, er, offs, deg, csr, out, N);
}

// Round 3
// 637.922 us; speedup vs baseline: 1.1709x; 1.1709x over previous
//
#include <hip/hip_runtime.h>
#include <hip/hip_bf16.h>
#include <stdint.h>

#define IN_F   64
#define OH     256      // OUT * H
#define SLOPE  0.2f
#define TN     32       // nodes per block in projection

__device__ __forceinline__ float bf2f(unsigned short u) {
    union { unsigned int i; float f; } c; c.i = ((unsigned int)u) << 16; return c.f;
}
__device__ __forceinline__ unsigned short f2bf(float f) {
    union { float f; unsigned int i; } c; c.f = f;
    unsigned int lsb = (c.i >> 16) & 1u;
    c.i += 0x7fffu + lsb;                 // round-to-nearest-even
    return (unsigned short)(c.i >> 16);
}

// ---------------- K0: fold a_l/a_r into W: Wl[8][64], bl[8] ----------------
// e_l[n,h] = feat[n,:]·Wl[h,:] + bl[h];  e_r uses rows 4..7.
__global__ __launch_bounds__(256) void prep_kernel(
    const float* __restrict__ W, const float* __restrict__ bias,
    const float* __restrict__ a_l, const float* __restrict__ a_r,
    float* __restrict__ Wl, float* __restrict__ bl)
{
    int t = threadIdx.x;
    for (int id = t; id < 512; id += 256) {
        int x = id >> 6, k = id & 63;
        int h = x & 3;
        const float* v = (x < 4) ? a_l : a_r;
        float s = 0.f;
        for (int d = 0; d < 64; d++) {
            int o = d * 4 + h;                  // a_? flat index = d*H + h
            s += v[o] * W[o * 64 + k];
        }
        Wl[id] = s;
    }
    if (t < 8) {
        int h = t & 3;
        const float* v = (t < 4) ? a_l : a_r;
        float s = 0.f;
        for (int d = 0; d < 64; d++) { int o = d * 4 + h; s += v[o] * bias[o]; }
        bl[t] = s;
    }
}

// ---------------- K1: zero deg + counter ----------------
__global__ __launch_bounds__(256) void zero_kernel(int* __restrict__ a, int* __restrict__ b, int N) {
    int i = blockIdx.x * 256 + threadIdx.x;
    if (i < N) { a[i] = 0; b[i] = 0; }
}

// ---------------- K2: Z_bf16 = feat @ W^T + bias, fused e_l/e_r ----------------
__global__ __launch_bounds__(256) void proj_kernel(
    const float4* __restrict__ feat4,
    const float4* __restrict__ W4,
    const float* __restrict__ bias,
    const float* __restrict__ Wl, const float* __restrict__ bl,
    unsigned short* __restrict__ Zb,
    float* __restrict__ el, float* __restrict__ er, int N)
{
    __shared__ float featS[TN][IN_F + 4];   // stride 68 floats: elr reads conflict-free
    __shared__ float WlS[8][64];
    int t = threadIdx.x;
    int nodeBase = blockIdx.x * TN;

    for (int p = t; p < TN * 16; p += 256) {
        int n = p >> 4, kk = p & 15;
        int gn = nodeBase + n;
        float4 v = make_float4(0.f, 0.f, 0.f, 0.f);
        if (gn < N) v = feat4[(size_t)gn * 16 + kk];
        float* dst = &featS[n][kk * 4];
        dst[0] = v.x; dst[1] = v.y; dst[2] = v.z; dst[3] = v.w;
    }
    for (int p = t; p < 512; p += 256) WlS[p >> 6][p & 63] = Wl[p];

    float Wf[64];
    #pragma unroll
    for (int q = 0; q < 16; q++) {
        float4 w = W4[t * 16 + q];
        Wf[q * 4 + 0] = w.x; Wf[q * 4 + 1] = w.y;
        Wf[q * 4 + 2] = w.z; Wf[q * 4 + 3] = w.w;
    }
    float b = bias[t];
    __syncthreads();

    for (int n = 0; n < TN; n++) {
        int gn = nodeBase + n;
        if (gn >= N) break;
        float a = b;
        #pragma unroll
        for (int k = 0; k < 64; k++) a += featS[n][k] * Wf[k];
        Zb[(size_t)gn * OH + t] = f2bf(a);
    }

    // epilogue: e_l / e_r  (32 nodes x 8 outputs == 256 threads)
    int n2 = t >> 3, x = t & 7;
    int gn2 = nodeBase + n2;
    if (gn2 < N) {
        float e = bl[x];
        #pragma unroll
        for (int k = 0; k < 64; k++) e += featS[n2][k] * WlS[x][k];
        if (x < 4) el[(size_t)gn2 * 4 + x] = e;
        else       er[(size_t)gn2 * 4 + (x - 4)] = e;
    }
}

// ---------------- K3: degree histogram ----------------
__global__ __launch_bounds__(256) void hist_kernel(const int* __restrict__ row, int* __restrict__ deg, int E) {
    int e = blockIdx.x * 256 + threadIdx.x;
    if (e < E) atomicAdd(&deg[row[e]], 1);
}

// ---------------- K4: per-chunk sums (chunk = 1024) ----------------
__global__ __launch_bounds__(256) void scan_sums(const int* __restrict__ deg, int* __restrict__ bsums, int N) {
    __shared__ int lds[256];
    int t = threadIdx.x;
    int base = blockIdx.x * 1024;
    int v = 0;
    for (int q = 0; q < 4; q++) { int g = base + t * 4 + q; if (g < N) v += deg[g]; }
    lds[t] = v; __syncthreads();
    for (int off = 128; off >= 1; off >>= 1) {
        if (t < off) lds[t] += lds[t + off];
        __syncthreads();
    }
    if (t == 0) bsums[blockIdx.x] = lds[0];
}

// ---------------- K5: exclusive scan of chunk sums ----------------
__global__ void scan_top(int* __restrict__ bsums, int nb) {
    if (blockIdx.x == 0 && threadIdx.x == 0) {
        int run = 0;
        for (int i = 0; i < nb; i++) { int v = bsums[i]; bsums[i] = run; run += v; }
    }
}

// ---------------- K6: per-chunk exclusive scan -> offsets ----------------
__global__ __launch_bounds__(256) void scan_chunks(
    const int* __restrict__ deg, const int* __restrict__ bsums,
    int* __restrict__ offs, int N)
{
    __shared__ int lds[256];
    int t = threadIdx.x;
    int base = blockIdx.x * 1024;
    int vals[4]; int s = 0;
    for (int q = 0; q < 4; q++) { int g = base + t * 4 + q; vals[q] = (g < N) ? deg[g] : 0; s += vals[q]; }
    lds[t] = s; __syncthreads();
    for (int off = 1; off < 256; off <<= 1) {
        int add = (t >= off) ? lds[t - off] : 0;
        __syncthreads();
        lds[t] += add;
        __syncthreads();
    }
    int prefix = bsums[blockIdx.x] + (t > 0 ? lds[t - 1] : 0);
    for (int q = 0; q < 4; q++) {
        int g = base + t * 4 + q;
        if (g < N) { offs[g] = prefix; prefix += vals[q]; }
    }
}

// ---------------- K7: scatter edges into CSR by destination ----------------
__global__ __launch_bounds__(256) void scatter_kernel(
    const int* __restrict__ row, const int* __restrict__ col,
    const int* __restrict__ offs, int* __restrict__ cnt,
    int* __restrict__ csr, int E)
{
    int e = blockIdx.x * 256 + threadIdx.x;
    if (e < E) {
        int r = row[e];
        int pos = offs[r] + atomicAdd(&cnt[r], 1);
        csr[pos] = col[e];
    }
}

// ---------------- K8: single-pass (flash) softmax + aggregation, bf16 Z ----------------
__global__ __launch_bounds__(256) void gat_aggregate(
    const unsigned short* __restrict__ Zb, const float* __restrict__ el,
    const float* __restrict__ er, const int* __restrict__ offs,
    const int* __restrict__ deg, const int* __restrict__ csr,
    float* __restrict__ out, int N)
{
    __shared__ float s_al[64 * 4];
    __shared__ int   s_col[64];
    __shared__ float s_pm[16];   // per-wave per-head partial (max)
    __shared__ float s_ps[16];   // per-wave per-head partial (sum)

    int i = blockIdx.x;
    int t = threadIdx.x;
    int lane = t & 63, w = t >> 6;
    int j = t >> 2, h = t & 3;
    int start = offs[i], dg = deg[i];
    float elh = el[(size_t)i * 4 + h];

    float m = -3.0e38f, l = 0.f, acc = 0.f;

    for (int base = 0; base < dg; base += 64) {
        int cnt = min(64, dg - base);
        float sc = -3.0e38f;
        if (j < cnt) {
            int c = csr[start + base + j];
            sc = elh + er[(size_t)c * 4 + h];
            sc = sc > 0.f ? sc : SLOPE * sc;
            if (h == 0) s_col[j] = c;
        }
        // per-head max: butterfly over lanes stride 4..32 (16 lanes share h per wave)
        float v = sc;
        v = fmaxf(v, __shfl_xor(v, 4));
        v = fmaxf(v, __shfl_xor(v, 8));
        v = fmaxf(v, __shfl_xor(v, 16));
        v = fmaxf(v, __shfl_xor(v, 32));
        if (lane < 4) s_pm[w * 4 + lane] = v;      // lane == h for lane<4
        __syncthreads();
        float mc = fmaxf(fmaxf(s_pm[h], s_pm[4 + h]), fmaxf(s_pm[8 + h], s_pm[12 + h]));
        float mnew = fmaxf(m, mc);

        float a = 0.f;
        if (j < cnt) { a = __expf(sc - mnew); s_al[j * 4 + h] = a; }
        float sv = a;
        sv += __shfl_xor(sv, 4);
        sv += __shfl_xor(sv, 8);
        sv += __shfl_xor(sv, 16);
        sv += __shfl_xor(sv, 32);
        if (lane < 4) s_ps[w * 4 + lane] = sv;
        __syncthreads();                            // also publishes s_al / s_col
        float lc = s_ps[h] + s_ps[4 + h] + s_ps[8 + h] + s_ps[12 + h];

        float r = __expf(m - mnew);                 // first chunk: exp(-inf) = 0
        l = l * r + lc;
        acc *= r;
        for (int q = 0; q < cnt; q++)
            acc += s_al[q * 4 + h] * bf2f(Zb[(size_t)s_col[q] * OH + t]);
        m = mnew;
        __syncthreads();                            // protect s_al/s_col/s_pm for next chunk
    }
    out[(size_t)i * OH + t] = (l > 0.f) ? acc / l : 0.f;
}

// ---------------- launch ----------------
extern "C" void kernel_launch(void* const* d_in, const int* in_sizes, int n_in,
                              void* d_out, int out_size, void* d_ws, size_t ws_size,
                              hipStream_t stream)
{
    const float* feat  = (const float*)d_in[0];
    const float* W     = (const float*)d_in[1];
    const float* bias  = (const float*)d_in[2];
    const float* a_l   = (const float*)d_in[3];
    const float* a_r   = (const float*)d_in[4];
    const int*   row   = (const int*)d_in[5];
    const int*   col   = (const int*)d_in[6];
    float* out = (float*)d_out;

    int N = in_sizes[0] / IN_F;
    int E = in_sizes[5];

    char* ws = (char*)d_ws;
    size_t off = 0;
    auto alloc = [&](size_t bytes) -> void* {
        void* p = (void*)(ws + off);
        off += (bytes + 255) & ~(size_t)255;
        return p;
    };
    unsigned short* Zb = (unsigned short*)alloc((size_t)N * OH * sizeof(unsigned short)); // 51.2 MB
    float* el    = (float*)alloc((size_t)N * 4 * sizeof(float));
    float* er    = (float*)alloc((size_t)N * 4 * sizeof(float));
    float* Wl    = (float*)alloc(512 * sizeof(float));
    float* bl    = (float*)alloc(8 * sizeof(float));
    int*   deg   = (int*)alloc((size_t)N * sizeof(int));
    int*   cnt   = (int*)alloc((size_t)N * sizeof(int));
    int*   offs  = (int*)alloc((size_t)N * sizeof(int));
    int*   bsums = (int*)alloc(4096);
    int*   csr   = (int*)alloc((size_t)E * sizeof(int));
    (void)ws_size; (void)n_in; (void)out_size;

    int NB = (N + 1023) / 1024;

    prep_kernel<<<1, 256, 0, stream>>>(W, bias, a_l, a_r, Wl, bl);
    zero_kernel<<<(N + 255) / 256, 256, 0, stream>>>(deg, cnt, N);
    proj_kernel<<<(N + TN - 1) / TN, 256, 0, stream>>>(
        (const float4*)feat, (const float4*)W, bias, Wl, bl, Zb, el, er, N);
    hist_kernel<<<(E + 255) / 256, 256, 0, stream>>>(row, deg, E);
    scan_sums<<<NB, 256, 0, stream>>>(deg, bsums, N);
    scan_top<<<1, 64, 0, stream>>>(bsums, NB);
    scan_chunks<<<NB, 256, 0, stream>>>(deg, bsums, offs, N);
    scatter_kernel<<<(E + 255) / 256, 256, 0, stream>>>(row, col, offs, cnt, csr, E);
    gat_aggregate<<<N, 256, 0, stream>>>(Zb, el, er, offs, deg, csr, out, N);
}

// Round 5
// 485.631 us; speedup vs baseline: 1.5380x; 1.3136x over previous
//
#include <hip/hip_runtime.h>
#include <hip/hip_bf16.h>
#include <stdint.h>

#define SLOPE  0.2f
#define PN     64       // nodes per proj block

union FU { float f; unsigned int u; };
__device__ __forceinline__ float ubits(unsigned int u) { FU c; c.u = u; return c.f; }
__device__ __forceinline__ unsigned short f2bf(float f) {
    FU c; c.f = f;
    unsigned int lsb = (c.u >> 16) & 1u;
    c.u += 0x7fffu + lsb;                 // round-to-nearest-even
    return (unsigned short)(c.u >> 16);
}

// ---------------- K0: prep ----------------
// blocks 0..63: Wt[k][c'] = bf16(W[o][k]) with h-major channel c' (o = (c'&63)*4 + (c'>>6))
// block 64:     Wl[8][64], bl[8] (a_l/a_r folded into W), biasP[c'] (permuted bias)
__global__ __launch_bounds__(256) void prep_kernel(
    const float* __restrict__ W, const float* __restrict__ bias,
    const float* __restrict__ a_l, const float* __restrict__ a_r,
    unsigned short* __restrict__ Wt, float* __restrict__ biasP,
    float* __restrict__ Wl, float* __restrict__ bl)
{
    int t = threadIdx.x;
    if (blockIdx.x < 64) {
        int g = blockIdx.x * 256 + t;       // 16384 elements
        int k = g >> 8, cp = g & 255;
        int o = (cp & 63) * 4 + (cp >> 6);
        Wt[k * 256 + cp] = f2bf(W[o * 64 + k]);
    } else {
        for (int id = t; id < 512; id += 256) {
            int x = id >> 6, k = id & 63;
            int h = x & 3;
            const float* v = (x < 4) ? a_l : a_r;
            float s = 0.f;
            for (int d = 0; d < 64; d++) {
                int o = d * 4 + h;
                s += v[o] * W[o * 64 + k];
            }
            Wl[id] = s;
        }
        if (t < 8) {
            int h = t & 3;
            const float* v = (t < 4) ? a_l : a_r;
            float s = 0.f;
            for (int d = 0; d < 64; d++) { int o = d * 4 + h; s += v[o] * bias[o]; }
            bl[t] = s;
        }
        {
            int cp = t;
            int o = (cp & 63) * 4 + (cp >> 6);
            biasP[cp] = bias[o];
        }
    }
}

// ---------------- K1: zero deg + counter ----------------
__global__ __launch_bounds__(256) void zero_kernel(int* __restrict__ a, int* __restrict__ b, int N) {
    int i = blockIdx.x * 256 + threadIdx.x;
    if (i < N) { a[i] = 0; b[i] = 0; }
}

// ---------------- K2: proj — Zb(h-major bf16) = feat @ W^T + bias, fused el/er ----------------
__global__ __launch_bounds__(256) void proj_kernel(
    const float4* __restrict__ feat4,
    const uint4* __restrict__ Wt4,      // [64][32] uint4 (8 bf16 each), h-major channels
    const float* __restrict__ biasP,
    const float* __restrict__ Wl, const float* __restrict__ bl,
    unsigned short* __restrict__ Zb,
    float* __restrict__ el, float* __restrict__ er, int N)
{
    __shared__ float          fT[64][68];        // [k][node] fp32
    __shared__ unsigned short wT[64][264];       // [k][c'] bf16
    __shared__ float          WlS[8][68];
    __shared__ float          blS[8];

    int t = threadIdx.x;
    int nodeBase = blockIdx.x * PN;

    for (int p = t; p < 64 * 32; p += 256) {
        int k = p >> 5, cu = p & 31;
        *(uint4*)&wT[k][cu * 8] = Wt4[p];
    }
    for (int p = t; p < PN * 16; p += 256) {
        int n = p >> 4, kq = p & 15;
        int gn = nodeBase + n;
        float4 v = make_float4(0.f, 0.f, 0.f, 0.f);
        if (gn < N) v = feat4[(size_t)gn * 16 + kq];
        fT[kq * 4 + 0][n] = v.x; fT[kq * 4 + 1][n] = v.y;
        fT[kq * 4 + 2][n] = v.z; fT[kq * 4 + 3][n] = v.w;
    }
    for (int p = t; p < 512; p += 256) WlS[p >> 6][p & 63] = Wl[p];
    if (t < 8) blS[t] = bl[t];
    __syncthreads();

    int cg = t & 31;     // channel group: c' = cg*8 .. cg*8+7
    int ng = t >> 5;     // node group:    n  = ng*8 .. ng*8+7

    float bj[8];
    {
        float4 b0 = *(const float4*)&biasP[cg * 8];
        float4 b1 = *(const float4*)&biasP[cg * 8 + 4];
        bj[0] = b0.x; bj[1] = b0.y; bj[2] = b0.z; bj[3] = b0.w;
        bj[4] = b1.x; bj[5] = b1.y; bj[6] = b1.z; bj[7] = b1.w;
    }
    float acc[8][8];
    #pragma unroll
    for (int u = 0; u < 8; u++)
        #pragma unroll
        for (int j = 0; j < 8; j++) acc[u][j] = bj[j];

    for (int k = 0; k < 64; k++) {
        float4 fa = *(const float4*)&fT[k][ng * 8];
        float4 fb = *(const float4*)&fT[k][ng * 8 + 4];
        uint4  wv = *(const uint4*)&wT[k][cg * 8];
        float f[8] = { fa.x, fa.y, fa.z, fa.w, fb.x, fb.y, fb.z, fb.w };
        float w[8];
        w[0] = ubits(wv.x << 16); w[1] = ubits(wv.x & 0xffff0000u);
        w[2] = ubits(wv.y << 16); w[3] = ubits(wv.y & 0xffff0000u);
        w[4] = ubits(wv.z << 16); w[5] = ubits(wv.z & 0xffff0000u);
        w[6] = ubits(wv.w << 16); w[7] = ubits(wv.w & 0xffff0000u);
        #pragma unroll
        for (int u = 0; u < 8; u++)
            #pragma unroll
            for (int j = 0; j < 8; j++)
                acc[u][j] += f[u] * w[j];
    }

    #pragma unroll
    for (int u = 0; u < 8; u++) {
        int gn = nodeBase + ng * 8 + u;
        if (gn < N) {
            unsigned int pk[4];
            #pragma unroll
            for (int j = 0; j < 4; j++)
                pk[j] = (unsigned int)f2bf(acc[u][2 * j]) |
                        ((unsigned int)f2bf(acc[u][2 * j + 1]) << 16);
            uint4 sv = make_uint4(pk[0], pk[1], pk[2], pk[3]);
            *(uint4*)(Zb + (size_t)gn * 256 + cg * 8) = sv;
        }
    }

    // epilogue: el/er (fp32, from fp32 fT)
    for (int r = 0; r < 2; r++) {
        int id = t + 256 * r;
        int n = id >> 3, x = id & 7;
        int gn = nodeBase + n;
        if (gn < N) {
            float e = blS[x];
            #pragma unroll 8
            for (int k = 0; k < 64; k++) e += fT[k][n] * WlS[x][k];
            if (x < 4) el[(size_t)gn * 4 + x] = e;
            else       er[(size_t)gn * 4 + (x - 4)] = e;
        }
    }
}

// ---------------- K3: degree histogram ----------------
__global__ __launch_bounds__(256) void hist_kernel(const int* __restrict__ row, int* __restrict__ deg, int E) {
    int e = blockIdx.x * 256 + threadIdx.x;
    if (e < E) atomicAdd(&deg[row[e]], 1);
}

// ---------------- K4: per-chunk sums (chunk = 1024) ----------------
__global__ __launch_bounds__(256) void scan_sums(const int* __restrict__ deg, int* __restrict__ bsums, int N) {
    __shared__ int lds[256];
    int t = threadIdx.x;
    int base = blockIdx.x * 1024;
    int v = 0;
    for (int q = 0; q < 4; q++) { int g = base + t * 4 + q; if (g < N) v += deg[g]; }
    lds[t] = v; __syncthreads();
    for (int off = 128; off >= 1; off >>= 1) {
        if (t < off) lds[t] += lds[t + off];
        __syncthreads();
    }
    if (t == 0) bsums[blockIdx.x] = lds[0];
}

// ---------------- K5: parallel exclusive scan of chunk sums (nb <= 256) ----------------
__global__ __launch_bounds__(256) void scan_top(int* __restrict__ bsums, int nb) {
    __shared__ int s[256];
    int t = threadIdx.x;
    s[t] = (t < nb) ? bsums[t] : 0;
    __syncthreads();
    for (int off = 1; off < 256; off <<= 1) {
        int v = (t >= off) ? s[t - off] : 0;
        __syncthreads();
        s[t] += v;
        __syncthreads();
    }
    if (t < nb) bsums[t] = (t > 0) ? s[t - 1] : 0;
}

// ---------------- K6: per-chunk exclusive scan -> offsets ----------------
__global__ __launch_bounds__(256) void scan_chunks(
    const int* __restrict__ deg, const int* __restrict__ bsums,
    int* __restrict__ offs, int N)
{
    __shared__ int lds[256];
    int t = threadIdx.x;
    int base = blockIdx.x * 1024;
    int vals[4]; int s = 0;
    for (int q = 0; q < 4; q++) { int g = base + t * 4 + q; vals[q] = (g < N) ? deg[g] : 0; s += vals[q]; }
    lds[t] = s; __syncthreads();
    for (int off = 1; off < 256; off <<= 1) {
        int add = (t >= off) ? lds[t - off] : 0;
        __syncthreads();
        lds[t] += add;
        __syncthreads();
    }
    int prefix = bsums[blockIdx.x] + (t > 0 ? lds[t - 1] : 0);
    for (int q = 0; q < 4; q++) {
        int g = base + t * 4 + q;
        if (g < N) { offs[g] = prefix; prefix += vals[q]; }
    }
}

// ---------------- K7: scatter edges into CSR by destination ----------------
__global__ __launch_bounds__(256) void scatter_kernel(
    const int* __restrict__ row, const int* __restrict__ col,
    const int* __restrict__ offs, int* __restrict__ cnt,
    int* __restrict__ csr, int E)
{
    int e = blockIdx.x * 256 + threadIdx.x;
    if (e < E) {
        int r = row[e];
        int pos = offs[r] + atomicAdd(&cnt[r], 1);
        csr[pos] = col[e];
    }
}

// ---------------- K8: wave-per-destination flash softmax + aggregation ----------------
// Zb is h-major (c' = h*64+d). Lane owns c' = 4*lane .. 4*lane+3  (head hsel = lane>>4).
// Score side: lane = 4*e_local + hh (hh = lane&3).
// FIX (r4 bug): accumulator rescale must use head hsel's running max, not head hh's.
__global__ __launch_bounds__(256) void gat_aggregate(
    const unsigned short* __restrict__ Zb, const float* __restrict__ el,
    const float* __restrict__ er, const int* __restrict__ offs,
    const int* __restrict__ deg, const int* __restrict__ csr,
    float* __restrict__ out, int N)
{
    int lane = threadIdx.x & 63;
    int i = blockIdx.x * 4 + (threadIdx.x >> 6);
    if (i >= N) return;

    int start = offs[i], dg = deg[i];
    int eL = lane >> 2, hh = lane & 3;
    float elh = el[(size_t)i * 4 + hh];

    float m = -3.0e38f;       // running max for head hh (score side)
    float m_h = -3.0e38f;     // running max for head hsel (accumulator side)
    float l = 0.f;
    float a0 = 0.f, a1 = 0.f, a2 = 0.f, a3 = 0.f;
    int hsel = lane >> 4;     // head of this lane's output channels

    for (int base = 0; base < dg; base += 16) {
        int cnt = min(16, dg - base);
        float sc = -3.0e38f;
        int c = 0;
        if (eL < cnt) {
            c = csr[start + base + eL];
            float e = elh + er[(size_t)c * 4 + hh];
            sc = e > 0.f ? e : SLOPE * e;
        }
        // per-head max over e_local (butterfly over lane bits 2..5)
        float v = sc;
        v = fmaxf(v, __shfl_xor(v, 4));
        v = fmaxf(v, __shfl_xor(v, 8));
        v = fmaxf(v, __shfl_xor(v, 16));
        v = fmaxf(v, __shfl_xor(v, 32));
        float mnew = fmaxf(m, v);                 // head hh's new max
        float a = (eL < cnt) ? __expf(sc - mnew) : 0.f;
        float sv = a;
        sv += __shfl_xor(sv, 4);
        sv += __shfl_xor(sv, 8);
        sv += __shfl_xor(sv, 16);
        sv += __shfl_xor(sv, 32);
        // l is head hh's running expsum (self-consistent with m/mnew)
        l = l * __expf(m - mnew) + sv;
        m = mnew;

        // accumulator rescale in head hsel's frame
        float mn_h = __shfl(mnew, hsel);          // lane hsel has hh==hsel
        float r = __expf(m_h - mn_h);             // first chunk: exp(-huge)=0
        a0 *= r; a1 *= r; a2 *= r; a3 *= r;
        m_h = mn_h;

        for (int q = 0; q < cnt; q++) {
            int   cq = __shfl(c, q * 4);
            float al = __shfl(a, q * 4 + hsel);   // alpha rel. head hsel's max
            const uint2* zp = (const uint2*)(Zb + ((size_t)cq << 8));
            uint2 zw = zp[lane];
            a0 += al * ubits(zw.x << 16);
            a1 += al * ubits(zw.x & 0xffff0000u);
            a2 += al * ubits(zw.y << 16);
            a3 += al * ubits(zw.y & 0xffff0000u);
        }
    }

    float lh  = __shfl(l, hsel);                  // head hsel's expsum (rel. m_hsel)
    float inv = (lh > 0.f) ? 1.0f / lh : 0.f;
    // write back in ORIGINAL layout o = d*4 + h, d = 4*(lane&15)+u, h = hsel
    float* op = out + (size_t)i * 256;
    int dbase = 4 * (lane & 15);
    op[(dbase + 0) * 4 + hsel] = a0 * inv;
    op[(dbase + 1) * 4 + hsel] = a1 * inv;
    op[(dbase + 2) * 4 + hsel] = a2 * inv;
    op[(dbase + 3) * 4 + hsel] = a3 * inv;
}

// ---------------- launch ----------------
extern "C" void kernel_launch(void* const* d_in, const int* in_sizes, int n_in,
                              void* d_out, int out_size, void* d_ws, size_t ws_size,
                              hipStream_t stream)
{
    const float* feat  = (const float*)d_in[0];
    const float* W     = (const float*)d_in[1];
    const float* bias  = (const float*)d_in[2];
    const float* a_l   = (const float*)d_in[3];
    const float* a_r   = (const float*)d_in[4];
    const int*   row   = (const int*)d_in[5];
    const int*   col   = (const int*)d_in[6];
    float* out = (float*)d_out;

    int N = in_sizes[0] / 64;
    int E = in_sizes[5];

    char* ws = (char*)d_ws;
    size_t off = 0;
    auto alloc = [&](size_t bytes) -> void* {
        void* p = (void*)(ws + off);
        off += (bytes + 255) & ~(size_t)255;
        return p;
    };
    unsigned short* Zb    = (unsigned short*)alloc((size_t)N * 256 * sizeof(unsigned short));
    unsigned short* Wt    = (unsigned short*)alloc(64 * 256 * sizeof(unsigned short));
    float*          biasP = (float*)alloc(256 * sizeof(float));
    float* el    = (float*)alloc((size_t)N * 4 * sizeof(float));
    float* er    = (float*)alloc((size_t)N * 4 * sizeof(float));
    float* Wl    = (float*)alloc(512 * sizeof(float));
    float* bl    = (float*)alloc(8 * sizeof(float));
    int*   deg   = (int*)alloc((size_t)N * sizeof(int));
    int*   cnt   = (int*)alloc((size_t)N * sizeof(int));
    int*   offs  = (int*)alloc((size_t)N * sizeof(int));
    int*   bsums = (int*)alloc(4096);
    int*   csr   = (int*)alloc((size_t)E * sizeof(int));
    (void)ws_size; (void)n_in; (void)out_size;

    int NB = (N + 1023) / 1024;

    prep_kernel<<<65, 256, 0, stream>>>(W, bias, a_l, a_r, Wt, biasP, Wl, bl);
    zero_kernel<<<(N + 255) / 256, 256, 0, stream>>>(deg, cnt, N);
    proj_kernel<<<(N + PN - 1) / PN, 256, 0, stream>>>(
        (const float4*)feat, (const uint4*)Wt, biasP, Wl, bl, Zb, el, er, N);
    hist_kernel<<<(E + 255) / 256, 256, 0, stream>>>(row, deg, E);
    scan_sums<<<NB, 256, 0, stream>>>(deg, bsums, N);
    scan_top<<<1, 256, 0, stream>>>(bsums, NB);
    scan_chunks<<<NB, 256, 0, stream>>>(deg, bsums, offs, N);
    scatter_kernel<<<(E + 255) / 256, 256, 0, stream>>>(row, col, offs, cnt, csr, E);
    gat_aggregate<<<(N + 3) / 4, 256, 0, stream>>>(Zb, el, er, offs, deg, csr, out, N);
}

// Round 6
// 482.431 us; speedup vs baseline: 1.5482x; 1.0066x over previous
//
#include <hip/hip_runtime.h>
#include <hip/hip_bf16.h>
#include <stdint.h>

#define SLOPE  0.2f
#define PN     64       // nodes per proj block

union FU { float f; unsigned int u; };
__device__ __forceinline__ float ubits(unsigned int u) { FU c; c.u = u; return c.f; }
__device__ __forceinline__ unsigned short f2bf(float f) {
    FU c; c.f = f;
    unsigned int lsb = (c.u >> 16) & 1u;
    c.u += 0x7fffu + lsb;                 // round-to-nearest-even
    return (unsigned short)(c.u >> 16);
}

// ---------------- K0: prep + zero ----------------
// blocks 0..63:  Wt[k][c'] = bf16(W[o][k]) h-major channel c' (o = (c'&63)*4 + (c'>>6))
// block 64:      Wl[8][64], bl[8], biasP[c']
// blocks 65..:   zero deg/cnt
__global__ __launch_bounds__(256) void prep_kernel(
    const float* __restrict__ W, const float* __restrict__ bias,
    const float* __restrict__ a_l, const float* __restrict__ a_r,
    unsigned short* __restrict__ Wt, float* __restrict__ biasP,
    float* __restrict__ Wl, float* __restrict__ bl,
    int* __restrict__ deg, int* __restrict__ cnt, int N)
{
    int t = threadIdx.x;
    if (blockIdx.x < 64) {
        int g = blockIdx.x * 256 + t;       // 16384 elements
        int k = g >> 8, cp = g & 255;
        int o = (cp & 63) * 4 + (cp >> 6);
        Wt[k * 256 + cp] = f2bf(W[o * 64 + k]);
    } else if (blockIdx.x == 64) {
        for (int id = t; id < 512; id += 256) {
            int x = id >> 6, k = id & 63;
            int h = x & 3;
            const float* v = (x < 4) ? a_l : a_r;
            float s = 0.f;
            for (int d = 0; d < 64; d++) {
                int o = d * 4 + h;
                s += v[o] * W[o * 64 + k];
            }
            Wl[id] = s;
        }
        if (t < 8) {
            int h = t & 3;
            const float* v = (t < 4) ? a_l : a_r;
            float s = 0.f;
            for (int d = 0; d < 64; d++) { int o = d * 4 + h; s += v[o] * bias[o]; }
            bl[t] = s;
        }
        {
            int cp = t;
            int o = (cp & 63) * 4 + (cp >> 6);
            biasP[cp] = bias[o];
        }
    } else {
        int i = (blockIdx.x - 65) * 256 + t;
        if (i < N) { deg[i] = 0; cnt[i] = 0; }
    }
}

// ---------------- K2: proj — Zb(h-major bf16) = feat @ W^T + bias, fused el/er ----------------
__global__ __launch_bounds__(256) void proj_kernel(
    const float4* __restrict__ feat4,
    const uint4* __restrict__ Wt4,      // [64][32] uint4 (8 bf16 each), h-major channels
    const float* __restrict__ biasP,
    const float* __restrict__ Wl, const float* __restrict__ bl,
    unsigned short* __restrict__ Zb,
    float* __restrict__ el, float* __restrict__ er, int N)
{
    __shared__ float          fT[64][68];        // [k][node] fp32
    __shared__ unsigned short wT[64][264];       // [k][c'] bf16
    __shared__ float          WlS[8][68];
    __shared__ float          blS[8];

    int t = threadIdx.x;
    int nodeBase = blockIdx.x * PN;

    for (int p = t; p < 64 * 32; p += 256) {
        int k = p >> 5, cu = p & 31;
        *(uint4*)&wT[k][cu * 8] = Wt4[p];
    }
    for (int p = t; p < PN * 16; p += 256) {
        int n = p >> 4, kq = p & 15;
        int gn = nodeBase + n;
        float4 v = make_float4(0.f, 0.f, 0.f, 0.f);
        if (gn < N) v = feat4[(size_t)gn * 16 + kq];
        fT[kq * 4 + 0][n] = v.x; fT[kq * 4 + 1][n] = v.y;
        fT[kq * 4 + 2][n] = v.z; fT[kq * 4 + 3][n] = v.w;
    }
    for (int p = t; p < 512; p += 256) WlS[p >> 6][p & 63] = Wl[p];
    if (t < 8) blS[t] = bl[t];
    __syncthreads();

    int cg = t & 31;     // channel group: c' = cg*8 .. cg*8+7
    int ng = t >> 5;     // node group:    n  = ng*8 .. ng*8+7

    float bj[8];
    {
        float4 b0 = *(const float4*)&biasP[cg * 8];
        float4 b1 = *(const float4*)&biasP[cg * 8 + 4];
        bj[0] = b0.x; bj[1] = b0.y; bj[2] = b0.z; bj[3] = b0.w;
        bj[4] = b1.x; bj[5] = b1.y; bj[6] = b1.z; bj[7] = b1.w;
    }
    float acc[8][8];
    #pragma unroll
    for (int u = 0; u < 8; u++)
        #pragma unroll
        for (int j = 0; j < 8; j++) acc[u][j] = bj[j];

    for (int k = 0; k < 64; k++) {
        float4 fa = *(const float4*)&fT[k][ng * 8];
        float4 fb = *(const float4*)&fT[k][ng * 8 + 4];
        uint4  wv = *(const uint4*)&wT[k][cg * 8];
        float f[8] = { fa.x, fa.y, fa.z, fa.w, fb.x, fb.y, fb.z, fb.w };
        float w[8];
        w[0] = ubits(wv.x << 16); w[1] = ubits(wv.x & 0xffff0000u);
        w[2] = ubits(wv.y << 16); w[3] = ubits(wv.y & 0xffff0000u);
        w[4] = ubits(wv.z << 16); w[5] = ubits(wv.z & 0xffff0000u);
        w[6] = ubits(wv.w << 16); w[7] = ubits(wv.w & 0xffff0000u);
        #pragma unroll
        for (int u = 0; u < 8; u++)
            #pragma unroll
            for (int j = 0; j < 8; j++)
                acc[u][j] += f[u] * w[j];
    }

    #pragma unroll
    for (int u = 0; u < 8; u++) {
        int gn = nodeBase + ng * 8 + u;
        if (gn < N) {
            unsigned int pk[4];
            #pragma unroll
            for (int j = 0; j < 4; j++)
                pk[j] = (unsigned int)f2bf(acc[u][2 * j]) |
                        ((unsigned int)f2bf(acc[u][2 * j + 1]) << 16);
            uint4 sv = make_uint4(pk[0], pk[1], pk[2], pk[3]);
            *(uint4*)(Zb + (size_t)gn * 256 + cg * 8) = sv;
        }
    }

    // epilogue: el/er (fp32, from fp32 fT)
    for (int r = 0; r < 2; r++) {
        int id = t + 256 * r;
        int n = id >> 3, x = id & 7;
        int gn = nodeBase + n;
        if (gn < N) {
            float e = blS[x];
            #pragma unroll 8
            for (int k = 0; k < 64; k++) e += fT[k][n] * WlS[x][k];
            if (x < 4) el[(size_t)gn * 4 + x] = e;
            else       er[(size_t)gn * 4 + (x - 4)] = e;
        }
    }
}

// ---------------- K3: degree histogram ----------------
__global__ __launch_bounds__(256) void hist_kernel(const int* __restrict__ row, int* __restrict__ deg, int E) {
    int e = blockIdx.x * 256 + threadIdx.x;
    if (e < E) atomicAdd(&deg[row[e]], 1);
}

// ---------------- K4: per-chunk sums (chunk = 1024) ----------------
__global__ __launch_bounds__(256) void scan_sums(const int* __restrict__ deg, int* __restrict__ bsums, int N) {
    __shared__ int lds[256];
    int t = threadIdx.x;
    int base = blockIdx.x * 1024;
    int v = 0;
    for (int q = 0; q < 4; q++) { int g = base + t * 4 + q; if (g < N) v += deg[g]; }
    lds[t] = v; __syncthreads();
    for (int off = 128; off >= 1; off >>= 1) {
        if (t < off) lds[t] += lds[t + off];
        __syncthreads();
    }
    if (t == 0) bsums[blockIdx.x] = lds[0];
}

// ---------------- K5: parallel exclusive scan of chunk sums (nb <= 256) ----------------
__global__ __launch_bounds__(256) void scan_top(int* __restrict__ bsums, int nb) {
    __shared__ int s[256];
    int t = threadIdx.x;
    s[t] = (t < nb) ? bsums[t] : 0;
    __syncthreads();
    for (int off = 1; off < 256; off <<= 1) {
        int v = (t >= off) ? s[t - off] : 0;
        __syncthreads();
        s[t] += v;
        __syncthreads();
    }
    if (t < nb) bsums[t] = (t > 0) ? s[t - 1] : 0;
}

// ---------------- K6: per-chunk exclusive scan -> offsets ----------------
__global__ __launch_bounds__(256) void scan_chunks(
    const int* __restrict__ deg, const int* __restrict__ bsums,
    int* __restrict__ offs, int N)
{
    __shared__ int lds[256];
    int t = threadIdx.x;
    int base = blockIdx.x * 1024;
    int vals[4]; int s = 0;
    for (int q = 0; q < 4; q++) { int g = base + t * 4 + q; vals[q] = (g < N) ? deg[g] : 0; s += vals[q]; }
    lds[t] = s; __syncthreads();
    for (int off = 1; off < 256; off <<= 1) {
        int add = (t >= off) ? lds[t - off] : 0;
        __syncthreads();
        lds[t] += add;
        __syncthreads();
    }
    int prefix = bsums[blockIdx.x] + (t > 0 ? lds[t - 1] : 0);
    for (int q = 0; q < 4; q++) {
        int g = base + t * 4 + q;
        if (g < N) { offs[g] = prefix; prefix += vals[q]; }
    }
}

// ---------------- K7: scatter edges into CSR by destination ----------------
__global__ __launch_bounds__(256) void scatter_kernel(
    const int* __restrict__ row, const int* __restrict__ col,
    const int* __restrict__ offs, int* __restrict__ cnt,
    int* __restrict__ csr, int E)
{
    int e = blockIdx.x * 256 + threadIdx.x;
    if (e < E) {
        int r = row[e];
        int pos = offs[r] + atomicAdd(&cnt[r], 1);
        csr[pos] = col[e];
    }
}

// ---------------- K8: wave-per-destination flash softmax + aggregation ----------------
// Zb is h-major (c' = h*64+d). Lane owns c' = 4*lane .. 4*lane+3  (head hsel = lane>>4).
// Score side: lane = 4*e_local + hh (hh = lane&3).
// Gather is a FIXED 16-trip unrolled loop (predication via a=0, c=0) so all 16
// wave-loads issue before consumption -> ~16 outstanding loads/wave.
__global__ __launch_bounds__(256) void gat_aggregate(
    const unsigned short* __restrict__ Zb, const float* __restrict__ el,
    const float* __restrict__ er, const int* __restrict__ offs,
    const int* __restrict__ deg, const int* __restrict__ csr,
    float* __restrict__ out, int N)
{
    int lane = threadIdx.x & 63;
    int i = blockIdx.x * 4 + (threadIdx.x >> 6);
    if (i >= N) return;

    int start = offs[i], dg = deg[i];
    int eL = lane >> 2, hh = lane & 3;
    float elh = el[(size_t)i * 4 + hh];

    float m = -3.0e38f;       // running max for head hh (score side)
    float m_h = -3.0e38f;     // running max for head hsel (accumulator side)
    float l = 0.f;
    float a0 = 0.f, a1 = 0.f, a2 = 0.f, a3 = 0.f;
    int hsel = lane >> 4;     // head of this lane's output channels

    for (int base = 0; base < dg; base += 16) {
        int cnt = min(16, dg - base);
        float sc = -3.0e38f;
        int c = 0;
        if (eL < cnt) {
            c = csr[start + base + eL];
            float e = elh + er[(size_t)c * 4 + hh];
            sc = e > 0.f ? e : SLOPE * e;
        }
        // per-head max over e_local (butterfly over lane bits 2..5)
        float v = sc;
        v = fmaxf(v, __shfl_xor(v, 4));
        v = fmaxf(v, __shfl_xor(v, 8));
        v = fmaxf(v, __shfl_xor(v, 16));
        v = fmaxf(v, __shfl_xor(v, 32));
        float mnew = fmaxf(m, v);                 // head hh's new max
        float a = (eL < cnt) ? __expf(sc - mnew) : 0.f;
        float sv = a;
        sv += __shfl_xor(sv, 4);
        sv += __shfl_xor(sv, 8);
        sv += __shfl_xor(sv, 16);
        sv += __shfl_xor(sv, 32);
        // l is head hh's running expsum (self-consistent with m/mnew)
        l = l * __expf(m - mnew) + sv;
        m = mnew;

        // accumulator rescale in head hsel's frame
        float mn_h = __shfl(mnew, hsel);          // lane hsel has hh==hsel
        float r = __expf(m_h - mn_h);             // first chunk: exp(-huge)=0
        a0 *= r; a1 *= r; a2 *= r; a3 *= r;
        m_h = mn_h;

        // broadcast edge ids + alphas (inactive slots: c=0 valid addr, al=0)
        int   cq[16];
        float alq[16];
        #pragma unroll
        for (int q = 0; q < 16; q++) {
            cq[q]  = __shfl(c, q * 4);
            alq[q] = __shfl(a, q * 4 + hsel);
        }
        uint2 zw[16];
        #pragma unroll
        for (int q = 0; q < 16; q++)
            zw[q] = ((const uint2*)(Zb + ((size_t)cq[q] << 8)))[lane];
        #pragma unroll
        for (int q = 0; q < 16; q++) {
            float al = alq[q];
            a0 += al * ubits(zw[q].x << 16);
            a1 += al * ubits(zw[q].x & 0xffff0000u);
            a2 += al * ubits(zw[q].y << 16);
            a3 += al * ubits(zw[q].y & 0xffff0000u);
        }
    }

    float lh  = __shfl(l, hsel);                  // head hsel's expsum (rel. m_hsel)
    float inv = (lh > 0.f) ? 1.0f / lh : 0.f;
    // write back in ORIGINAL layout o = d*4 + h, d = 4*(lane&15)+u, h = hsel
    // non-temporal: out is never re-read -> don't evict Zb from L2/L3
    float* op = out + (size_t)i * 256;
    int dbase = 4 * (lane & 15);
    __builtin_nontemporal_store(a0 * inv, &op[(dbase + 0) * 4 + hsel]);
    __builtin_nontemporal_store(a1 * inv, &op[(dbase + 1) * 4 + hsel]);
    __builtin_nontemporal_store(a2 * inv, &op[(dbase + 2) * 4 + hsel]);
    __builtin_nontemporal_store(a3 * inv, &op[(dbase + 3) * 4 + hsel]);
}

// ---------------- launch ----------------
extern "C" void kernel_launch(void* const* d_in, const int* in_sizes, int n_in,
                              void* d_out, int out_size, void* d_ws, size_t ws_size,
                              hipStream_t stream)
{
    const float* feat  = (const float*)d_in[0];
    const float* W     = (const float*)d_in[1];
    const float* bias  = (const float*)d_in[2];
    const float* a_l   = (const float*)d_in[3];
    const float* a_r   = (const float*)d_in[4];
    const int*   row   = (const int*)d_in[5];
    const int*   col   = (const int*)d_in[6];
    float* out = (float*)d_out;

    int N = in_sizes[0] / 64;
    int E = in_sizes[5];

    char* ws = (char*)d_ws;
    size_t off = 0;
    auto alloc = [&](size_t bytes) -> void* {
        void* p = (void*)(ws + off);
        off += (bytes + 255) & ~(size_t)255;
        return p;
    };
    unsigned short* Zb    = (unsigned short*)alloc((size_t)N * 256 * sizeof(unsigned short));
    unsigned short* Wt    = (unsigned short*)alloc(64 * 256 * sizeof(unsigned short));
    float*          biasP = (float*)alloc(256 * sizeof(float));
    float* el    = (float*)alloc((size_t)N * 4 * sizeof(float));
    float* er    = (float*)alloc((size_t)N * 4 * sizeof(float));
    float* Wl    = (float*)alloc(512 * sizeof(float));
    float* bl    = (float*)alloc(8 * sizeof(float));
    int*   deg   = (int*)alloc((size_t)N * sizeof(int));
    int*   cnt   = (int*)alloc((size_t)N * sizeof(int));
    int*   offs  = (int*)alloc((size_t)N * sizeof(int));
    int*   bsums = (int*)alloc(4096);
    int*   csr   = (int*)alloc((size_t)E * sizeof(int));
    (void)ws_size; (void)n_in; (void)out_size;

    int NB = (N + 1023) / 1024;
    int ZB = (N + 255) / 256;

    prep_kernel<<<65 + ZB, 256, 0, stream>>>(W, bias, a_l, a_r, Wt, biasP, Wl, bl, deg, cnt, N);
    proj_kernel<<<(N + PN - 1) / PN, 256, 0, stream>>>(
        (const float4*)feat, (const uint4*)Wt, biasP, Wl, bl, Zb, el, er, N);
    hist_kernel<<<(E + 255) / 256, 256, 0, stream>>>(row, deg, E);
    scan_sums<<<NB, 256, 0, stream>>>(deg, bsums, N);
    scan_top<<<1, 256, 0, stream>>>(bsums, NB);
    scan_chunks<<<NB, 256, 0, stream>>>(deg, bsums, offs, N);
    scatter_kernel<<<(E + 255) / 256, 256, 0, stream>>>(row, col, offs, cnt, csr, E);
    gat_aggregate<<<(N + 3) / 4, 256, 0, stream>>>(Zb, el, er, offs, deg, csr, out, N);
}